// Round 1
// baseline (413.388 us; speedup 1.0000x reference)
//
#include <hip/hip_runtime.h>

// Octree2Col: masked gather
//   out[n,k,:] = neigh[n,k] >= 0 ? data[neigh[n,k], :] : 0
// N=100000, K=27, C=128, fp32. Write-BW-bound (~1.38 GB out).
//
// Layout trick: C = 128 floats = 32 float4. For flat float4 index g over the
// output, row = g>>5 (flat n*K+k index into neigh), c4 = g&31. No div-by-27.

__global__ __launch_bounds__(256) void octree2col_gather(
    const float4* __restrict__ data,   // [N, 32]  (N x C as float4)
    const int*    __restrict__ neigh,  // [N*K]
    float4*       __restrict__ out,    // [N*K, 32]
    int total_f4)                      // N*K*(C/4)
{
    int stride = gridDim.x * blockDim.x;
    for (int g = blockIdx.x * blockDim.x + threadIdx.x; g < total_f4; g += stride) {
        int row = g >> 5;          // index into neigh (n*K + k)
        int c4  = g & 31;          // float4 column within the C=128 row
        int idx = neigh[row];      // 32 consecutive lanes broadcast-read same addr
        float4 v = make_float4(0.f, 0.f, 0.f, 0.f);
        if (idx >= 0) {
            v = data[(long long)idx * 32 + c4];   // 512B-contiguous per row
        }
        out[g] = v;                // fully coalesced stream write
    }
}

extern "C" void kernel_launch(void* const* d_in, const int* in_sizes, int n_in,
                              void* d_out, int out_size, void* d_ws, size_t ws_size,
                              hipStream_t stream) {
    const float4* data  = (const float4*)d_in[0];
    const int*    neigh = (const int*)d_in[1];
    float4*       out   = (float4*)d_out;

    int total_f4 = out_size / 4;               // N*K*C / 4
    const int threads = 256;
    int blocks = (total_f4 + threads - 1) / threads;
    if (blocks > 2048) blocks = 2048;          // grid-stride; 32 waves/CU

    octree2col_gather<<<blocks, threads, 0, stream>>>(data, neigh, out, total_f4);
}

// Round 2
// 396.300 us; speedup vs baseline: 1.0431x; 1.0431x over previous
//
#include <hip/hip_runtime.h>

// Octree2Col: masked gather
//   out[n,k,:] = neigh[n,k] >= 0 ? data[neigh[n,k], :] : 0
// N=100000, K=27, C=128, fp32. Write-BW-bound (~1.38 GB out, ~62 MB in).
//
// Round 2 changes vs Round 1 (413 us):
//  - nontemporal stores for `out`: store stream never re-read; stop it from
//    evicting the 51 MB `data` array out of L2/L3 (gather stays cache-resident).
//  - manual 4x batching: 4 independent neigh loads -> 4 independent gathers
//    -> 4 stores per loop iteration (MLP; round 1 had one dependent chain).

typedef float floatx4 __attribute__((ext_vector_type(4)));

__global__ __launch_bounds__(256) void octree2col_gather(
    const floatx4* __restrict__ data,   // [N, 32]  (N x C as float4)
    const int*     __restrict__ neigh,  // [N*K]
    floatx4*       __restrict__ out,    // [N*K, 32]
    int total_f4)                       // N*K*(C/4)
{
    const int step = gridDim.x * blockDim.x;
    int g = blockIdx.x * blockDim.x + threadIdx.x;

    // main loop: 4 elements per thread-iteration, stride `step` apart
    for (; g + 3 * step < total_f4; g += 4 * step) {
        const int g0 = g, g1 = g + step, g2 = g + 2 * step, g3 = g + 3 * step;

        // 4 independent broadcast reads (32 consecutive lanes share one row)
        const int i0 = neigh[g0 >> 5];
        const int i1 = neigh[g1 >> 5];
        const int i2 = neigh[g2 >> 5];
        const int i3 = neigh[g3 >> 5];

        floatx4 v0 = {0.f, 0.f, 0.f, 0.f};
        floatx4 v1 = v0, v2 = v0, v3 = v0;

        // 4 independent gathers (512B-contiguous per row, random rows; L3-resident)
        if (i0 >= 0) v0 = data[(long long)i0 * 32 + (g0 & 31)];
        if (i1 >= 0) v1 = data[(long long)i1 * 32 + (g1 & 31)];
        if (i2 >= 0) v2 = data[(long long)i2 * 32 + (g2 & 31)];
        if (i3 >= 0) v3 = data[(long long)i3 * 32 + (g3 & 31)];

        // nontemporal coalesced stream writes (bypass cache pollution)
        __builtin_nontemporal_store(v0, &out[g0]);
        __builtin_nontemporal_store(v1, &out[g1]);
        __builtin_nontemporal_store(v2, &out[g2]);
        __builtin_nontemporal_store(v3, &out[g3]);
    }

    // tail
    for (; g < total_f4; g += step) {
        const int idx = neigh[g >> 5];
        floatx4 v = {0.f, 0.f, 0.f, 0.f};
        if (idx >= 0) v = data[(long long)idx * 32 + (g & 31)];
        __builtin_nontemporal_store(v, &out[g]);
    }
}

extern "C" void kernel_launch(void* const* d_in, const int* in_sizes, int n_in,
                              void* d_out, int out_size, void* d_ws, size_t ws_size,
                              hipStream_t stream) {
    const floatx4* data  = (const floatx4*)d_in[0];
    const int*     neigh = (const int*)d_in[1];
    floatx4*       out   = (floatx4*)d_out;

    int total_f4 = out_size / 4;               // N*K*C / 4
    const int threads = 256;
    int blocks = (total_f4 + threads - 1) / threads;
    if (blocks > 2048) blocks = 2048;          // 8 wg/CU -> 32 waves/CU (max occ)

    octree2col_gather<<<blocks, threads, 0, stream>>>(data, neigh, out, total_f4);
}

// Round 3
// 330.547 us; speedup vs baseline: 1.2506x; 1.1989x over previous
//
#include <hip/hip_runtime.h>
#include <climits>

// Octree2Col: masked gather
//   out[n,k,:] = neigh[n,k] >= 0 ? data[neigh[n,k], :] : 0
// N=100000, K=27, C=128, fp32.
//
// Round 3: chunk-the-source scheme.
//   Round 2 evidence: 396 us ~= 2.7 GB @ 6.9 TB/s -> gather reads (1.3 GB)
//   all miss cache; the 1.38 GB write stream thrashes the memory-side L3,
//   evicting the 51 MB data array. Fix: process data in 4 MB chunks
//   (fits per-XCD L2). Pass p copies only output rows whose neigh falls in
//   chunk p, so gathers hit a hot L2 chunk. neigh is register-cached per wave
//   (read once); matching rows found by wave-uniform __ballot + bit-scan;
//   each 512 B row copied by a 32-lane half-wave as float4.
//   Chunks partition [0,N) and -1 rows are zero-filled -> each output row
//   written exactly once. No atomics, no workspace, deterministic.

typedef float floatx4 __attribute__((ext_vector_type(4)));

constexpr int ROWS_PER_CHUNK = 8192;   // 8192 rows * 512 B = 4 MB = per-XCD L2
constexpr int THREADS = 256;
constexpr int BLOCKS  = 2048;          // 8 blocks/CU * 256 CU: all co-resident
constexpr int WAVES   = BLOCKS * THREADS / 64;   // 8192 waves
constexpr int GPW     = 6;             // groups/wave: ceil(2.7e6/64 / 8192) = 6

__global__ __launch_bounds__(THREADS) void octree2col_chunked(
    const floatx4* __restrict__ data,   // [N, 32]  (N x C as float4)
    const int*     __restrict__ neigh,  // [N*K]
    floatx4*       __restrict__ out,    // [N*K, 32]
    int rows_total,                     // N*K
    int n_data_rows)                    // N
{
    const int wave = (blockIdx.x * THREADS + threadIdx.x) >> 6;
    const int lane = threadIdx.x & 63;
    const int half = lane >> 5;        // 0: handles r1, 1: handles r2
    const int c4   = lane & 31;        // float4 column within 512 B row

    const int ngroups = (rows_total + 63) >> 6;
    const int nchunks = (n_data_rows + ROWS_PER_CHUNK - 1) / ROWS_PER_CHUNK;

    // ---- load this wave's neigh values ONCE into registers (coalesced) ----
    int nv[GPW];
    int gbase[GPW];
#pragma unroll
    for (int i = 0; i < GPW; ++i) {
        const int g = wave + i * WAVES;          // strided group assignment
        gbase[i] = g << 6;
        const int row = gbase[i] + lane;
        nv[i] = (g < ngroups && row < rows_total) ? neigh[row] : INT_MIN;
    }

    // ---- zero-fill invalid rows (neigh == -1); rare ----
#pragma unroll
    for (int i = 0; i < GPW; ++i) {
        unsigned long long zm = __ballot(nv[i] == -1);
        while (zm) {
            int r1 = __builtin_ctzll(zm); zm &= zm - 1;
            int r2 = -1;
            if (zm) { r2 = __builtin_ctzll(zm); zm &= zm - 1; }
            const int r = half ? r2 : r1;
            if (r >= 0) {
                const long long row = gbase[i] + r;
                floatx4 z = {0.f, 0.f, 0.f, 0.f};
                __builtin_nontemporal_store(z, &out[row * 32 + c4]);
            }
        }
    }

    // ---- chunk passes: gather only rows whose idx is in the hot chunk ----
    for (int p = 0; p < nchunks; ++p) {
        const int lo = p * ROWS_PER_CHUNK;
#pragma unroll
        for (int i = 0; i < GPW; ++i) {
            unsigned long long m =
                __ballot((unsigned)(nv[i] - lo) < (unsigned)ROWS_PER_CHUNK);
            while (m) {
                int r1 = __builtin_ctzll(m); m &= m - 1;
                int r2 = -1;
                if (m) { r2 = __builtin_ctzll(m); m &= m - 1; }
                const int r  = half ? r2 : r1;
                const int rs = r < 0 ? 0 : r;
                const int idx = __shfl(nv[i], rs);   // broadcast row's index
                if (r >= 0) {
                    const long long row = gbase[i] + r;
                    floatx4 v = data[(long long)idx * 32 + c4];  // L2-hot chunk
                    __builtin_nontemporal_store(v, &out[row * 32 + c4]);
                }
            }
        }
        __syncthreads();   // keep block's waves on the same chunk (L2 locality)
    }
}

extern "C" void kernel_launch(void* const* d_in, const int* in_sizes, int n_in,
                              void* d_out, int out_size, void* d_ws, size_t ws_size,
                              hipStream_t stream) {
    const floatx4* data  = (const floatx4*)d_in[0];
    const int*     neigh = (const int*)d_in[1];
    floatx4*       out   = (floatx4*)d_out;

    const int rows_total  = in_sizes[1];        // N*K
    const int n_data_rows = in_sizes[0] / 128;  // N (C=128)

    octree2col_chunked<<<BLOCKS, THREADS, 0, stream>>>(
        data, neigh, out, rows_total, n_data_rows);
}

// Round 4
// 327.713 us; speedup vs baseline: 1.2614x; 1.0086x over previous
//
#include <hip/hip_runtime.h>
#include <climits>

// Octree2Col: masked gather
//   out[n,k,:] = neigh[n,k] >= 0 ? data[neigh[n,k], :] : 0
// N=100000, K=27, C=128, fp32. Write floor ~1.38 GB -> ~215 us @ 6.5 TB/s.
//
// Round 4: bin-by-chunk + XCD-owned chunks.
//   Round 3 (330 us) still paid ~0.7 GB extra HBM read: every chunk pass ran
//   on all 8 XCDs, so each chunk was fetched into 8 private L2s (51 MB x 8),
//   and the 1.38 GB store stream thrashes the memory-side L3 so it doesn't
//   absorb the replication. Fix: K1 bins output rows into per-chunk lists
//   (LDS-aggregated atomics, d_ws); K2 assigns each chunk to exactly ONE XCD
//   (blockIdx&7) -> each 1 MB chunk read from HBM once, gathers hit that
//   XCD's L2. Bucket-order within a list is schedule-dependent but output
//   values are order-independent -> deterministic output.
//   Falls back to the round-3 chunked kernel if ws_size is too small.

typedef float floatx4 __attribute__((ext_vector_type(4)));

constexpr int CH_LOG     = 11;    // 2048 data rows per bucket = 1 MB chunk
constexpr int K1_THREADS = 1024;  // big blocks -> long runs per bucket (write coalescing)
constexpr int K2_BLOCKS  = 2048;  // 8 per CU; bid&7 = XCD, bid>>3 = 0..255 local
constexpr int K2_THREADS = 256;

// -------- tiny init: zero bucket cursors (avoid memset-in-capture risk) ----
__global__ void k_zero(int* __restrict__ cursor, int NB) {
    if ((int)threadIdx.x < NB) cursor[threadIdx.x] = 0;
}

// -------- K1: bin output rows by data-row bucket; zero-fill invalid --------
__global__ __launch_bounds__(K1_THREADS) void k_bin(
    const int* __restrict__ neigh,   // [R]
    const floatx4* __restrict__ data,
    floatx4*   __restrict__ out,
    int2*      __restrict__ pairs,   // [NB * cap] (row, idx)
    int*       __restrict__ cursor,  // [NB], zeroed
    int R, int NB, int cap)
{
    extern __shared__ int lds[];     // l_cnt[NB], l_base[NB]
    int* l_cnt  = lds;
    int* l_base = lds + NB;
    for (int i = threadIdx.x; i < NB; i += K1_THREADS) l_cnt[i] = 0;
    __syncthreads();

    const int r = blockIdx.x * K1_THREADS + threadIdx.x;
    int idx = INT_MIN, b = 0, rank = 0;
    if (r < R) {
        idx = neigh[r];
        if (idx >= 0) {
            b = idx >> CH_LOG;
            rank = atomicAdd(&l_cnt[b], 1);     // intra-block rank in bucket
        }
    }
    __syncthreads();
    for (int i = threadIdx.x; i < NB; i += K1_THREADS)
        l_base[i] = atomicAdd(&cursor[i], l_cnt[i]);  // reserve block's range
    __syncthreads();

    if (idx >= 0) {
        const int slot = l_base[b] + rank;
        if (slot < cap) {
            pairs[(size_t)b * cap + slot] = make_int2(r, idx);
        } else {
            // statistical overflow safety net: copy directly (cache-cold, ~never)
            const floatx4* s = data + (size_t)idx * 32;
            floatx4*       d = out  + (size_t)r   * 32;
            for (int c = 0; c < 32; ++c) __builtin_nontemporal_store(s[c], &d[c]);
        }
    } else if (idx == -1) {
        // invalid neighbor: zero-fill (uniform randint(-1,N): ~R/N rows total)
        const floatx4 z = {0.f, 0.f, 0.f, 0.f};
        floatx4* d = out + (size_t)r * 32;
        for (int c = 0; c < 32; ++c) __builtin_nontemporal_store(z, &d[c]);
    }
}

// -------- K2: per-XCD chunk ownership; half-wave copies one 512 B row ------
__global__ __launch_bounds__(K2_THREADS) void k_copy(
    const floatx4* __restrict__ data,
    floatx4*       __restrict__ out,
    const int2*    __restrict__ pairs,
    const int*     __restrict__ cursor,
    int NB, int cap)
{
    const int hw   = threadIdx.x >> 5;   // half-wave id 0..7
    const int c4   = threadIdx.x & 31;   // float4 column in 512 B row
    const int xcd  = blockIdx.x & 7;     // MI355X round-robin XCD mapping
    const int lblk = blockIdx.x >> 3;    // 0..255 within this XCD

    const int NB_full = NB & ~7;

    // buckets owned by this XCD: chunk lives in exactly one L2
    for (int b = xcd; b < NB_full; b += 8) {
        int cnt = cursor[b]; if (cnt > cap) cnt = cap;
        const int lo = (int)(((long long)cnt * lblk)       >> 8);
        const int hi = (int)(((long long)cnt * (lblk + 1)) >> 8);
        const int2* pb = pairs + (size_t)b * cap;
        for (int e = lo + hw; e < hi; e += 8) {
            const int2 pr = pb[e];                              // broadcast 8B
            const floatx4 v = data[(size_t)pr.y * 32 + c4];     // L2-hot chunk
            __builtin_nontemporal_store(v, &out[(size_t)pr.x * 32 + c4]);
        }
    }
    // leftover buckets (NB % 8): split across ALL blocks for load balance
    for (int b = NB_full; b < NB; ++b) {
        int cnt = cursor[b]; if (cnt > cap) cnt = cap;
        const int lo = (int)((long long)cnt * blockIdx.x       / K2_BLOCKS);
        const int hi = (int)((long long)cnt * (blockIdx.x + 1) / K2_BLOCKS);
        const int2* pb = pairs + (size_t)b * cap;
        for (int e = lo + hw; e < hi; e += 8) {
            const int2 pr = pb[e];
            const floatx4 v = data[(size_t)pr.y * 32 + c4];
            __builtin_nontemporal_store(v, &out[(size_t)pr.x * 32 + c4]);
        }
    }
}

// ---------------- fallback (round-3 chunked kernel, 330 us) ----------------
constexpr int ROWS_PER_CHUNK = 8192;
constexpr int FB_THREADS = 256;
constexpr int FB_BLOCKS  = 2048;
constexpr int FB_WAVES   = FB_BLOCKS * FB_THREADS / 64;
constexpr int GPW        = 6;

__global__ __launch_bounds__(FB_THREADS) void octree2col_chunked(
    const floatx4* __restrict__ data, const int* __restrict__ neigh,
    floatx4* __restrict__ out, int rows_total, int n_data_rows)
{
    const int wave = (blockIdx.x * FB_THREADS + threadIdx.x) >> 6;
    const int lane = threadIdx.x & 63;
    const int half = lane >> 5;
    const int c4   = lane & 31;
    const int ngroups = (rows_total + 63) >> 6;
    const int nchunks = (n_data_rows + ROWS_PER_CHUNK - 1) / ROWS_PER_CHUNK;

    int nv[GPW]; int gbase[GPW];
#pragma unroll
    for (int i = 0; i < GPW; ++i) {
        const int g = wave + i * FB_WAVES;
        gbase[i] = g << 6;
        const int row = gbase[i] + lane;
        nv[i] = (g < ngroups && row < rows_total) ? neigh[row] : INT_MIN;
    }
#pragma unroll
    for (int i = 0; i < GPW; ++i) {
        unsigned long long zm = __ballot(nv[i] == -1);
        while (zm) {
            int r1 = __builtin_ctzll(zm); zm &= zm - 1;
            int r2 = -1;
            if (zm) { r2 = __builtin_ctzll(zm); zm &= zm - 1; }
            const int r = half ? r2 : r1;
            if (r >= 0) {
                const long long row = gbase[i] + r;
                floatx4 z = {0.f, 0.f, 0.f, 0.f};
                __builtin_nontemporal_store(z, &out[row * 32 + c4]);
            }
        }
    }
    for (int p = 0; p < nchunks; ++p) {
        const int lo = p * ROWS_PER_CHUNK;
#pragma unroll
        for (int i = 0; i < GPW; ++i) {
            unsigned long long m =
                __ballot((unsigned)(nv[i] - lo) < (unsigned)ROWS_PER_CHUNK);
            while (m) {
                int r1 = __builtin_ctzll(m); m &= m - 1;
                int r2 = -1;
                if (m) { r2 = __builtin_ctzll(m); m &= m - 1; }
                const int r  = half ? r2 : r1;
                const int rs = r < 0 ? 0 : r;
                const int idx = __shfl(nv[i], rs);
                if (r >= 0) {
                    const long long row = gbase[i] + r;
                    floatx4 v = data[(long long)idx * 32 + c4];
                    __builtin_nontemporal_store(v, &out[row * 32 + c4]);
                }
            }
        }
        __syncthreads();
    }
}

// ---------------------------------------------------------------------------
extern "C" void kernel_launch(void* const* d_in, const int* in_sizes, int n_in,
                              void* d_out, int out_size, void* d_ws, size_t ws_size,
                              hipStream_t stream) {
    const floatx4* data  = (const floatx4*)d_in[0];
    const int*     neigh = (const int*)d_in[1];
    floatx4*       out   = (floatx4*)d_out;

    const int R = in_sizes[1];          // N*K output rows
    const int N = in_sizes[0] / 128;    // data rows (C=128)
    const int NB = (N + (1 << CH_LOG) - 1) >> CH_LOG;   // 49 buckets

    // per-full-bucket expected entries = R * 2048 / N; cap = 1.25x, 64-aligned
    long long mean = (((long long)R << CH_LOG) + N - 1) / N;
    int cap = (int)((mean * 5 + 3) / 4);
    cap = (cap + 63) & ~63;
    const size_t need = 1024 + (size_t)NB * (size_t)cap * sizeof(int2);

    if (ws_size >= need && NB <= 1024) {
        int*  cursor = (int*)d_ws;
        int2* pairs  = (int2*)((char*)d_ws + 1024);

        k_zero<<<1, 1024, 0, stream>>>(cursor, NB);

        const int k1_blocks = (R + K1_THREADS - 1) / K1_THREADS;
        const size_t lds = 2 * (size_t)NB * sizeof(int);
        k_bin<<<k1_blocks, K1_THREADS, lds, stream>>>(
            neigh, data, out, pairs, cursor, R, NB, cap);

        k_copy<<<K2_BLOCKS, K2_THREADS, 0, stream>>>(
            data, out, pairs, cursor, NB, cap);
    } else {
        octree2col_chunked<<<FB_BLOCKS, FB_THREADS, 0, stream>>>(
            data, neigh, out, R, N);
    }
}